// Round 9
// baseline (176.868 us; speedup 1.0000x reference)
//
#include <hip/hip_runtime.h>
#include <math.h>

#define NPTS 4096
#define KNN 10
#define CAP 48          // group-8 bound is <=80; overflow -> exact full rescan
#define TAU_SLACK 1e-4f // covers key-vs-d2 rounding skew (~2e-6 abs)
#define NRM_N (8 * 3 * NPTS)
#define QPB 64          // queries per block (1024 blocks)
#define CHUNK 1024      // points staged per LDS round (16 KB)
#define NCH (NPTS / CHUNK)

__device__ __forceinline__ float med3f(float a, float b, float c) {
    return __builtin_amdgcn_fmed3f(a, b, c);
}

// ---------------- packed dual-FP32 key evaluation (VOP3P) -------------------
// R9: the two queries per thread evaluate the same candidate with different
// coefficients -> pack into v_pk_fma_f32 (CDNA2+ packed fp32, present on
// gfx950). op_sel broadcasts the candidate's x/y/z/w out of the float4's
// natural (x,y)/(z,w) register pairs -- no repack movs. Each half executes
// an IEEE-754 FMA identical to v_fma_f32 -> keys are BIT-IDENTICAL to the
// scalar chain -> tau, collection set, and output unchanged (absmax 0.0).
typedef float f32x2 __attribute__((ext_vector_type(2)));

// d = {fma(a.x, b.x, c.y), fma(a.y, b.x, c.y)}   (b bcast lo, c bcast hi)
__device__ __forceinline__ f32x2 pk_fma_blo_chi(f32x2 a, f32x2 b, f32x2 c) {
    f32x2 d;
    asm("v_pk_fma_f32 %0, %1, %2, %3 op_sel:[0,0,1] op_sel_hi:[1,0,1]"
        : "=v"(d) : "v"(a), "v"(b), "v"(c));
    return d;
}
// d = {fma(a.x, b.y, c.x), fma(a.y, b.y, c.y)}   (b bcast hi)
__device__ __forceinline__ f32x2 pk_fma_bhi(f32x2 a, f32x2 b, f32x2 c) {
    f32x2 d;
    asm("v_pk_fma_f32 %0, %1, %2, %3 op_sel:[0,1,0] op_sel_hi:[1,1,1]"
        : "=v"(d) : "v"(a), "v"(b), "v"(c));
    return d;
}
// d = {fma(a.x, b.x, c.x), fma(a.y, b.x, c.y)}   (b bcast lo)
__device__ __forceinline__ f32x2 pk_fma_blo(f32x2 a, f32x2 b, f32x2 c) {
    f32x2 d;
    asm("v_pk_fma_f32 %0, %1, %2, %3 op_sel:[0,0,0] op_sel_hi:[1,0,1]"
        : "=v"(d) : "v"(a), "v"(b), "v"(c));
    return d;
}
// packed key pair for queries (c0,c1): key[c] = fma(m2z[c],z,fma(m2y[c],y,fma(m2x[c],x,w)))
__device__ __forceinline__ f32x2 pk_keys(f32x2 M2X, f32x2 M2Y, f32x2 M2Z,
                                         f32x2 XY, f32x2 ZW) {
    f32x2 k = pk_fma_blo_chi(M2X, XY, ZW);   // fma(m2x[c], x, w)
    k = pk_fma_bhi(M2Y, XY, k);              // fma(m2y[c], y, .)
    k = pk_fma_blo(M2Z, ZW, k);              // fma(m2z[c], z, .)
    return k;
}

// ---------------- LAPACK building blocks (f32, faithful to netlib) ----------
// Fully predicated straight-line leaves (R5, verified absmax 0.0).

__device__ __forceinline__ float slapy2_(float x, float y) {
    float ax = fabsf(x), ay = fabsf(y);
    float w = fmaxf(ax, ay), z = fminf(ax, ay);
    float t = z / w;
    float full = w * sqrtf(1.f + t * t);
    return (z == 0.f) ? w : full;
}

__device__ __forceinline__ void slartg_(float f, float g, float* c, float* s, float* r) {
    float f1 = fabsf(f);
    float d = sqrtf(f * f + g * g);
    float rr = copysignf(d, f);
    float ce = f1 / d;
    float se = g / rr;
    bool gz = (g == 0.f), fz = (f == 0.f);
    *c = gz ? 1.f : (fz ? 0.f : ce);
    *s = gz ? 0.f : (fz ? copysignf(1.f, g) : se);
    *r = gz ? f   : (fz ? fabsf(g) : rr);
}

__device__ __forceinline__ void slaev2_(float a, float b, float c,
                                        float* rt1, float* rt2, float* cs1, float* sn1) {
    float sm = a + c;
    float df = a - c;
    float adf = fabsf(df);
    float tb = b + b;
    float ab = fabsf(tb);
    bool agtc = (fabsf(a) > fabsf(c));
    float acmx = agtc ? a : c;
    float acmn = agtc ? c : a;
    float t1 = ab / adf;  float rt_a = adf * sqrtf(1.f + t1 * t1);
    float t2 = adf / ab;  float rt_b = ab * sqrtf(1.f + t2 * t2);
    float rt_c = ab * sqrtf(2.f);
    float rt = (adf > ab) ? rt_a : ((adf < ab) ? rt_b : rt_c);

    float rt1n = 0.5f * (sm - rt);
    float rt1p = 0.5f * (sm + rt);
    float rt2n = (acmx / rt1n) * acmn - (b / rt1n) * b;
    float rt2p = (acmx / rt1p) * acmn - (b / rt1p) * b;
    int sgn1 = (sm < 0.f) ? -1 : 1;
    float r1 = (sm < 0.f) ? rt1n : ((sm > 0.f) ? rt1p : 0.5f * rt);
    float r2 = (sm < 0.f) ? rt2n : ((sm > 0.f) ? rt2p : -0.5f * rt);

    int sgn2 = (df >= 0.f) ? 1 : -1;
    float cs = (df >= 0.f) ? (df + rt) : (df - rt);
    float acs = fabsf(cs);
    float ct = -tb / cs;  float sn1a = 1.f / sqrtf(1.f + ct * ct);  float cs1a = ct * sn1a;
    float tn = -cs / tb;  float cs1b = 1.f / sqrtf(1.f + tn * tn);  float sn1b = tn * cs1b;
    float cs1v = (acs > ab) ? cs1a : ((ab == 0.f) ? 1.f : cs1b);
    float sn1v = (acs > ab) ? sn1a : ((ab == 0.f) ? 0.f : sn1b);
    bool flip = (sgn1 == sgn2);
    *cs1 = flip ? -sn1v : cs1v;
    *sn1 = flip ?  cs1v : sn1v;
    *rt1 = r1;
    *rt2 = r2;
}

// branchless register-select helpers (v_cndmask, never exec-mask branches)
__device__ __forceinline__ float g3v(float a0, float a1, float a2, int i) {
    return i == 0 ? a0 : (i == 1 ? a1 : a2);
}
__device__ __forceinline__ void s3v(float& a0, float& a1, float& a2, int i, float v) {
    a0 = (i == 0) ? v : a0;
    a1 = (i == 1) ? v : a1;
    a2 = (i == 2) ? v : a2;
}
__device__ __forceinline__ float g2v(float a0, float a1, int i) {
    return i == 0 ? a0 : a1;
}
__device__ __forceinline__ void s2v(float& a0, float& a1, int i, float v) {
    a0 = (i == 0) ? v : a0;
    a1 = (i == 1) ? v : a1;
}

// R8 (kept): all steqr3 rotations act on ADJACENT columns (jc, jc-1), jc in
// {1,2} -> 2-way selects instead of 3-way. Bit-exact (same expressions).
#define ZROT_ADJ(jc1, C, S)                                                      \
    { float t0_ = (jc1) ? z01 : z02, u0_ = (jc1) ? z00 : z01;                    \
      float nc0_ = (C) * t0_ - (S) * u0_;                                        \
      float nm0_ = (S) * t0_ + (C) * u0_;                                        \
      z00 = (jc1) ? nm0_ : z00; z01 = (jc1) ? nc0_ : nm0_; z02 = (jc1) ? z02 : nc0_; \
      float t1_ = (jc1) ? z11 : z12, u1_ = (jc1) ? z10 : z11;                    \
      float nc1_ = (C) * t1_ - (S) * u1_;                                        \
      float nm1_ = (S) * t1_ + (C) * u1_;                                        \
      z10 = (jc1) ? nm1_ : z10; z11 = (jc1) ? nc1_ : nm1_; z12 = (jc1) ? z12 : nc1_; \
      float t2_ = (jc1) ? z21 : z22, u2_ = (jc1) ? z20 : z21;                    \
      float nc2_ = (C) * t2_ - (S) * u2_;                                        \
      float nm2_ = (S) * t2_ + (C) * u2_;                                        \
      z20 = (jc1) ? nm2_ : z20; z21 = (jc1) ? nc2_ : nm2_; z22 = (jc1) ? z22 : nc2_; }

#define ZSWAP(ja, jb)                                                            \
    { float t0_ = g3v(z00, z01, z02, (ja));                                      \
      s3v(z00, z01, z02, (ja), g3v(z00, z01, z02, (jb)));                        \
      s3v(z00, z01, z02, (jb), t0_);                                             \
      float t1_ = g3v(z10, z11, z12, (ja));                                      \
      s3v(z10, z11, z12, (ja), g3v(z10, z11, z12, (jb)));                        \
      s3v(z10, z11, z12, (jb), t1_);                                             \
      float t2_ = g3v(z20, z21, z22, (ja));                                      \
      s3v(z20, z21, z22, (ja), g3v(z20, z21, z22, (jb)));                        \
      s3v(z20, z21, z22, (jb), t2_); }

__device__ void steqr3_reg(float& d0, float& d1, float& d2,
                           float& e0, float& e1,
                           float& z00, float& z01, float& z02,
                           float& z10, float& z11, float& z12,
                           float& z20, float& z21, float& z22) {
    const float eps    = 5.9604644775390625e-8f;  // 2^-24
    const float eps2   = eps * eps;
    const float safmin = 1.17549435e-38f;
    const int n = 3, nm1 = 2;
    const int nmaxit = 90;
    int jtot = 0, l1 = 1;
    int guard = 0;

#define DGET(i)    g3v(d0, d1, d2, (i))
#define DSET(i, v) s3v(d0, d1, d2, (i), (v))
#define EGET(i)    g2v(e0, e1, (i))
#define ESET(i, v) s2v(e0, e1, (i), (v))

    while (l1 <= n) {
        if (++guard > 600) break;
        if (l1 > 1) ESET(l1 - 2, 0.f);
        int m = n;
        if (l1 <= nm1) {
            for (int mm = l1; mm <= nm1; ++mm) {
                float tst = fabsf(EGET(mm - 1));
                if (tst == 0.f) { m = mm; break; }
                if (tst <= (sqrtf(fabsf(DGET(mm - 1))) * sqrtf(fabsf(DGET(mm)))) * eps) {
                    ESET(mm - 1, 0.f); m = mm; break;
                }
            }
        }
        int l = l1, lsv = l1, lend = m, lendsv = m;
        l1 = m + 1;
        if (lend == l) continue;
        float anorm = 0.f;
        for (int i = l; i <= lend; i++) anorm = fmaxf(anorm, fabsf(DGET(i - 1)));
        for (int i = l; i <= lend - 1; i++) anorm = fmaxf(anorm, fabsf(EGET(i - 1)));
        if (anorm == 0.f) continue;
        if (fabsf(DGET(lend - 1)) < fabsf(DGET(l - 1))) { lend = lsv; l = lendsv; }

        if (lend > l) {
            for (;;) {
                if (++guard > 600) return;
                int m2 = lend;
                if (l != lend) {
                    for (int mm = l; mm <= lend - 1; ++mm) {
                        float tst = EGET(mm - 1) * EGET(mm - 1);
                        if (tst <= (eps2 * fabsf(DGET(mm - 1))) * fabsf(DGET(mm)) + safmin) { m2 = mm; break; }
                    }
                }
                if (m2 < lend) ESET(m2 - 1, 0.f);
                float p = DGET(l - 1);
                if (m2 == l) {
                    DSET(l - 1, p); l = l + 1;
                    if (l <= lend) continue;
                    break;
                }
                if (m2 == l + 1) {
                    float rt1, rt2, c, s;
                    slaev2_(DGET(l - 1), EGET(l - 1), DGET(l), &rt1, &rt2, &c, &s);
                    ZROT_ADJ(l == 1, c, s);                 // cols (l, l-1)
                    DSET(l - 1, rt1); DSET(l, rt2); ESET(l - 1, 0.f);
                    l += 2;
                    if (l <= lend) continue;
                    break;
                }
                if (jtot == nmaxit) break;
                jtot++;
                float g = (DGET(l) - p) / (2.f * EGET(l - 1));
                float r = slapy2_(g, 1.f);
                g = DGET(m2 - 1) - p + EGET(l - 1) / (g + copysignf(r, g));
                float s = 1.f, c = 1.f;
                p = 0.f;
                float cs0 = 0.f, cs1 = 0.f, sn0 = 0.f, sn1 = 0.f;
                for (int i = m2 - 1; i >= l; --i) {
                    float f = s * EGET(i - 1);
                    float b = c * EGET(i - 1);
                    slartg_(g, f, &c, &s, &r);
                    if (i != m2 - 1) ESET(i, r);
                    g = DGET(i) - p;
                    r = (DGET(i - 1) - g) * s + 2.f * c * b;
                    p = s * r;
                    DSET(i, g + p);
                    g = c * r - b;
                    s2v(cs0, cs1, i - l, c); s2v(sn0, sn1, i - l, -s);
                }
                int nrot = m2 - l;
                for (int j = nrot; j >= 1; --j) {
                    float C = g2v(cs0, cs1, j - 1), S = g2v(sn0, sn1, j - 1);
                    ZROT_ADJ(l - 1 + j == 1, C, S);         // cols (l-1+j, l-2+j)
                }
                DSET(l - 1, DGET(l - 1) - p);
                ESET(l - 1, g);
            }
        } else {
            for (;;) {
                if (++guard > 600) return;
                int m2 = lend;
                if (l != lend) {
                    for (int mm = l; mm >= lend + 1; --mm) {
                        float tst = EGET(mm - 2) * EGET(mm - 2);
                        if (tst <= (eps2 * fabsf(DGET(mm - 1))) * fabsf(DGET(mm - 2)) + safmin) { m2 = mm; break; }
                    }
                }
                if (m2 > lend) ESET(m2 - 2, 0.f);
                float p = DGET(l - 1);
                if (m2 == l) {
                    DSET(l - 1, p); l = l - 1;
                    if (l >= lend) continue;
                    break;
                }
                if (m2 == l - 1) {
                    float rt1, rt2, c, s;
                    slaev2_(DGET(l - 2), EGET(l - 2), DGET(l - 1), &rt1, &rt2, &c, &s);
                    ZROT_ADJ(l == 2, c, s);                 // cols (l-1, l-2)
                    DSET(l - 2, rt1); DSET(l - 1, rt2); ESET(l - 2, 0.f);
                    l -= 2;
                    if (l >= lend) continue;
                    break;
                }
                if (jtot == nmaxit) break;
                jtot++;
                float g = (DGET(l - 2) - p) / (2.f * EGET(l - 2));
                float r = slapy2_(g, 1.f);
                g = DGET(m2 - 1) - p + EGET(l - 2) / (g + copysignf(r, g));
                float s = 1.f, c = 1.f;
                p = 0.f;
                float cs0 = 0.f, cs1 = 0.f, sn0 = 0.f, sn1 = 0.f;
                for (int i = m2; i <= l - 1; ++i) {
                    float f = s * EGET(i - 1);
                    float b = c * EGET(i - 1);
                    slartg_(g, f, &c, &s, &r);
                    if (i != m2) ESET(i - 2, r);
                    g = DGET(i - 1) - p;
                    r = (DGET(i) - g) * s + 2.f * c * b;
                    p = s * r;
                    DSET(i - 1, g + p);
                    g = c * r - b;
                    s2v(cs0, cs1, i - m2, c); s2v(sn0, sn1, i - m2, s);
                }
                int nrot = l - m2;
                for (int j = 1; j <= nrot; ++j) {
                    float C = g2v(cs0, cs1, j - 1), S = g2v(sn0, sn1, j - 1);
                    ZROT_ADJ(m2 - 1 + j == 1, C, S);        // cols (m2-1+j, m2-2+j)
                }
                DSET(l - 1, DGET(l - 1) - p);
                ESET(l - 2, g);
            }
        }
    }
    for (int ii = 2; ii <= n; ++ii) {
        int i = ii - 1, k = i;
        float p = DGET(i - 1);
        for (int j = ii; j <= n; ++j) {
            bool lt = (DGET(j - 1) < p);
            k = lt ? j : k;
            p = lt ? DGET(j - 1) : p;
        }
        DSET(k - 1, DGET(i - 1)); DSET(i - 1, p);
        ZSWAP(i - 1, k - 1);
    }
#undef DGET
#undef DSET
#undef EGET
#undef ESET
}

__device__ void eig_normal3(const float xs[KNN], const float ys[KNN], const float zs[KNN],
                            float out[3]) {
    float mx = 0.f, my = 0.f, mz = 0.f;
#pragma unroll
    for (int s = 0; s < KNN; s++) { mx += xs[s]; my += ys[s]; mz += zs[s]; }
    mx /= 10.0f; my /= 10.0f; mz /= 10.0f;

    float c00 = 0.f, c10 = 0.f, c20 = 0.f, c11 = 0.f, c21 = 0.f, c22 = 0.f;
#pragma unroll
    for (int s = 0; s < KNN; s++) {
        float dx = xs[s] - mx, dy = ys[s] - my, dz = zs[s] - mz;
        c00 = fmaf(dx, dx, c00);
        c10 = fmaf(dy, dx, c10);
        c20 = fmaf(dz, dx, c20);
        c11 = fmaf(dy, dy, c11);
        c21 = fmaf(dz, dy, c21);
        c22 = fmaf(dz, dz, c22);
    }
    c00 /= 10.0f; c10 /= 10.0f; c20 /= 10.0f; c11 /= 10.0f; c21 /= 10.0f; c22 /= 10.0f;

    float alpha = c10, x2 = c20;
    float xnorm = fabsf(x2);
    bool xz = (xnorm == 0.f);
    float beta_f = -copysignf(slapy2_(alpha, xnorm), alpha);
    float tau_f  = (beta_f - alpha) / beta_f;
    float v2_f   = x2 / (alpha - beta_f);
    float tau  = xz ? 0.f : tau_f;
    float v2   = xz ? 0.f : v2_f;
    float beta = xz ? alpha : beta_f;

    bool tz = (tau != 0.f);
    float p0 = tau * (c11 + c21 * v2);
    float p1 = tau * (c21 + c22 * v2);
    float aw = -0.5f * tau * (p0 + p1 * v2);
    float w0 = p0 + aw;
    float w1 = p1 + aw * v2;
    float d0c = c00;
    float d1c = tz ? ((c11 - w0) - w0)            : c11;
    float e1c = tz ? ((c21 - v2 * w0) - w1)       : c21;
    float d2c = tz ? ((c22 - v2 * w1) - w1 * v2)  : c22;
    float e0c = beta;

    float z00 = 1.f, z01 = 0.f, z02 = 0.f;
    float z10 = 0.f, z11 = 1.f, z12 = 0.f;
    float z20 = 0.f, z21 = 0.f, z22 = 1.f;
    steqr3_reg(d0c, d1c, d2c, e0c, e1c,
               z00, z01, z02, z10, z11, z12, z20, z21, z22);

    float y0 = z00, y1 = z10, y2 = z20;
    float t = tau * (y1 + v2 * y2);
    float y1b = y1 - t;
    float y2b = y2 - t * v2;
    out[0] = y0;
    out[1] = tz ? y1b : y1;
    out[2] = tz ? y2b : y2;
}

__device__ __forceinline__ void merge_round(float* v, int off) {
    float t[KNN];
#pragma unroll
    for (int i = 0; i < KNN; i++) t[i] = fminf(v[i], __shfl_xor(v[KNN - 1 - i], off));
#define CE(a, b) { float hi = fmaxf(t[a], t[b]); float lo = fminf(t[a], t[b]); t[a] = hi; t[b] = lo; }
    CE(0, 8) CE(1, 9)
    CE(0, 4) CE(1, 5) CE(2, 6) CE(3, 7)
    CE(0, 2) CE(1, 3) CE(4, 6) CE(5, 7)
    CE(0, 1) CE(2, 3) CE(4, 5) CE(6, 7) CE(8, 9)
#undef CE
#pragma unroll
    for (int i = 0; i < KNN; i++) v[i] = t[i];
}

// ---------------- kernel 1: kNN selection -> sorted top-10 indices ----------
// R5-verified structure (1024 blocks x 512 threads, c=2, chunked staging).
// R9 change: key evaluation packed via v_pk_fma_f32 (bit-identical keys).
__global__ __launch_bounds__(512, 8) void knn_idx_kernel(const float* __restrict__ pred,
                                                         const float* __restrict__ gt,
                                                         unsigned short* __restrict__ idxout,
                                                         float* __restrict__ out) {
    __shared__ float4 pts[CHUNK];                 // 16384 B
    __shared__ unsigned short spairs[QPB * CAP];  // 6144 B
    __shared__ int scnt[QPB];                     // 256 B

    int tid = threadIdx.x;
    int bid = blockIdx.x;
    if (bid == 0 && tid == 0) out[0] = 0.f;   // zero for eig_loss's atomicAdd
    int cloud = bid >> 9;       // 0..1
    int b = (bid >> 6) & 7;     // 0..7
    int chunkq = bid & 63;      // 0..63  query chunk

    const float* src = (cloud == 0 ? pred : gt) + (size_t)b * 3 * NPTS;

    int part = tid & 15;        // 0..15
    int qg = tid >> 4;          // 0..31
    int ql0 = qg * 2;
    int q0 = chunkq * QPB + ql0;

    if (tid < QPB) scnt[tid] = 0;   // consumed only after pass-2 barriers

    // query coords straight from global (identical bits to staged values)
    f32x2 M2X, M2Y, M2Z;
    {
        float x0 = src[q0], y0 = src[NPTS + q0], z0 = src[2 * NPTS + q0];
        float x1 = src[q0 + 1], y1 = src[NPTS + q0 + 1], z1 = src[2 * NPTS + q0 + 1];
        M2X = (f32x2){-2.f * x0, -2.f * x1};
        M2Y = (f32x2){-2.f * y0, -2.f * y1};
        M2Z = (f32x2){-2.f * z0, -2.f * z1};
    }

    // ---- pass 1: med3 chain over 8-candidate group-min keys (chunked) ------
    float v[2][KNN + 1];
#pragma unroll
    for (int c = 0; c < 2; c++) {
#pragma unroll
        for (int s = 0; s < KNN; s++) v[c][s] = INFINITY;
        v[c][KNN] = -INFINITY;
    }

    for (int h = 0; h < NCH; h++) {
        if (h) __syncthreads();           // previous chunk fully consumed
        for (int j2 = tid; j2 < CHUNK; j2 += 512) {
            int j = h * CHUNK + j2;
            float x = src[j], y = src[NPTS + j], z = src[2 * NPTS + j];
            float w = fmaf(z, z, fmaf(y, y, x * x));
            pts[j2] = make_float4(x, y, z, w);
        }
        __syncthreads();
#pragma unroll 2
        for (int g2 = 0; g2 < 8; g2++) {  // global group = h*8+g2, ascending
            int jb = part + 128 * g2;
            f32x2 M = (f32x2){INFINITY, INFINITY};
#pragma unroll
            for (int u = 0; u < 8; u++) {
                float4 p = pts[jb + 16 * u];
                f32x2 XY = (f32x2){p.x, p.y};
                f32x2 ZW = (f32x2){p.z, p.w};
                f32x2 K = pk_keys(M2X, M2Y, M2Z, XY, ZW);
                M.x = fminf(M.x, K.x);
                M.y = fminf(M.y, K.y);
            }
            float m[2] = {M.x, M.y};
#pragma unroll
            for (int c = 0; c < 2; c++)
#pragma unroll
                for (int s = 0; s < KNN; s++) v[c][s] = med3f(m[c], v[c][s], v[c][s + 1]);
        }
    }

    // ---- merge the 16 part-lists (4 xor rounds) -> tau ---------------------
    float tauS[2];
#pragma unroll
    for (int c = 0; c < 2; c++) {
        merge_round(v[c], 1);
        merge_round(v[c], 2);
        merge_round(v[c], 4);
        merge_round(v[c], 8);
        tauS[c] = v[c][0] + TAU_SLACK;
    }

    // ---- pass 2: collect idx with key <= tau+slack (restaged chunks) -------
    for (int h = 0; h < NCH; h++) {
        __syncthreads();                  // pass-1 (or prev collect) done
        for (int j2 = tid; j2 < CHUNK; j2 += 512) {
            int j = h * CHUNK + j2;
            float x = src[j], y = src[NPTS + j], z = src[2 * NPTS + j];
            float w = fmaf(z, z, fmaf(y, y, x * x));
            pts[j2] = make_float4(x, y, z, w);
        }
        __syncthreads();
#pragma unroll 2
        for (int mm = 0; mm < 64; mm++) { // j ascending per part, as before
            int j2 = part + 16 * mm;
            float4 p = pts[j2];
            f32x2 XY = (f32x2){p.x, p.y};
            f32x2 ZW = (f32x2){p.z, p.w};
            f32x2 K = pk_keys(M2X, M2Y, M2Z, XY, ZW);
            if (K.x <= tauS[0]) {
                int pos = atomicAdd(&scnt[ql0], 1);
                if (pos < CAP) spairs[ql0 * CAP + pos] = (unsigned short)(h * CHUNK + j2);
            }
            if (K.y <= tauS[1]) {
                int pos = atomicAdd(&scnt[ql0 + 1], 1);
                if (pos < CAP) spairs[(ql0 + 1) * CAP + pos] = (unsigned short)(h * CHUNK + j2);
            }
        }
    }
    __syncthreads();

    // ---- tail: exact top-10 by reference (d2, idx), wave 0, global reads ---
    if (tid < QPB) {
        int ql = tid;
        int qi = chunkq * QPB + ql;
        float qx = src[qi], qy = src[NPTS + qi], qz = src[2 * NPTS + qi];
        float qw = fmaf(qz, qz, fmaf(qy, qy, qx * qx));
        int cnt = scnt[ql];

        float bd[KNN]; int bi_[KNN];
#pragma unroll
        for (int s = 0; s < KNN; s++) { bd[s] = 3.4e38f; bi_[s] = 0; }
        float worst = 3.4e38f;
        int wslot = 0;
        if (cnt > CAP) {
            // overflow: exact full rescan from global (correctness net)
            for (int j = 0; j < NPTS; j++) {
                float x = src[j], y = src[NPTS + j], z = src[2 * NPTS + j];
                float w = fmaf(z, z, fmaf(y, y, x * x));
                float dot = fmaf(qz, z, fmaf(qy, y, qx * x));
                float d2 = (qw + w) - 2.f * dot;
                if (d2 < worst) {
#pragma unroll
                    for (int s = 0; s < KNN; s++) { if (s == wslot) { bd[s] = d2; bi_[s] = j; } }
                    float wm = bd[0]; int ws = 0;
#pragma unroll
                    for (int s = 1; s < KNN; s++) { if (bd[s] > wm) { wm = bd[s]; ws = s; } }
                    worst = wm; wslot = ws;
                }
            }
        } else {
            for (int t = 0; t < cnt; t++) {
                int j = spairs[ql * CAP + t];
                float x = src[j], y = src[NPTS + j], z = src[2 * NPTS + j];
                float w = fmaf(z, z, fmaf(y, y, x * x));
                float dot = fmaf(qz, z, fmaf(qy, y, qx * x));
                float d2 = (qw + w) - 2.f * dot;
                if (d2 < worst) {
#pragma unroll
                    for (int s = 0; s < KNN; s++) { if (s == wslot) { bd[s] = d2; bi_[s] = j; } }
                    float wm = bd[0]; int ws = 0;
#pragma unroll
                    for (int s = 1; s < KNN; s++) { if (bd[s] > wm) { wm = bd[s]; ws = s; } }
                    worst = wm; wslot = ws;
                }
            }
        }
        // sort by (d2, idx) ascending == jax.lax.top_k order
#pragma unroll
        for (int a = 0; a < KNN - 1; a++)
#pragma unroll
            for (int b2 = 0; b2 < KNN - 1 - a; b2++) {
                bool sw = (bd[b2] > bd[b2 + 1]) ||
                          (bd[b2] == bd[b2 + 1] && bi_[b2] > bi_[b2 + 1]);
                float d_lo = sw ? bd[b2 + 1] : bd[b2];
                float d_hi = sw ? bd[b2] : bd[b2 + 1];
                int   i_lo = sw ? bi_[b2 + 1] : bi_[b2];
                int   i_hi = sw ? bi_[b2] : bi_[b2 + 1];
                bd[b2] = d_lo; bd[b2 + 1] = d_hi; bi_[b2] = i_lo; bi_[b2 + 1] = i_hi;
            }
        size_t qglobal = ((size_t)cloud * 8 + b) * NPTS + qi;
#pragma unroll
        for (int s = 0; s < KNN; s++)
            idxout[qglobal * KNN + s] = (unsigned short)bi_[s];
    }
}

// ---------------- kernel 2: fused gather + cov + eig + loss -----------------
// R5-verified structure (512 blocks x 128 threads, wave0=pred/wave1=gt pairing
// through LDS, one atomicAdd per block). Latency/issue optimum at 1 wave/SIMD
// (R5/R6 model: I~18us, L~18us, k_opt=1). Body: R8 ZROT_ADJ.
#define PAIRS_PB 64
__global__ __launch_bounds__(128) void eig_loss_kernel(const float* __restrict__ pred,
                                                       const float* __restrict__ gt,
                                                       const unsigned short* __restrict__ idxin,
                                                       float* __restrict__ out) {
    __shared__ float nl[128][3];

    int t = threadIdx.x;
    int cloud = t >> 6;                        // wave 0: pred, wave 1: gt
    int pr = blockIdx.x * PAIRS_PB + (t & 63); // pair id 0..32767
    int b = pr >> 12;
    int pt = pr & 4095;
    const float* src = (cloud == 0 ? pred : gt) + (size_t)b * 3 * NPTS;
    size_t qglobal = ((size_t)cloud * 8 + b) * NPTS + pt;

    float xs[KNN], ys[KNN], zs[KNN];
#pragma unroll
    for (int s = 0; s < KNN; s++) {
        int j = idxin[qglobal * KNN + s];
        xs[s] = src[j]; ys[s] = src[NPTS + j]; zs[s] = src[2 * NPTS + j];
    }
    float nv[3];
    eig_normal3(xs, ys, zs, nv);
    nl[t][0] = nv[0]; nl[t][1] = nv[1]; nl[t][2] = nv[2];
    __syncthreads();

    if (t < 64) {
        float acc = 0.f;
#pragma unroll
        for (int k = 0; k < 3; k++) {
            float dd = nl[t][k] - nl[t + 64][k];
            acc = fmaf(dd, dd, acc);
        }
#pragma unroll
        for (int off = 32; off > 0; off >>= 1) acc += __shfl_down(acc, off);
        if (t == 0) atomicAdd(out, acc * (1.f / (float)NRM_N));
    }
}

// ---------------- R11-verbatim static fallback (ws-too-small path) ----------
__device__ void do_phase_static(const float* __restrict__ src, int chunk, int tid,
                                float2* sxy, float* sz, unsigned short* spairs, int* scnt,
                                float nv[3]) {
    for (int j = tid; j < NPTS; j += 512) {
        float x = src[j], y = src[NPTS + j], z = src[2 * NPTS + j];
        sxy[j] = make_float2(x, y);
        sz[j] = z;
    }
    if (tid < 128) scnt[tid] = 0;
    __syncthreads();

    int part = tid & 15;
    int qg = tid >> 4;
    int ql0 = qg * 4;
    int q0 = chunk * 128 + ql0;

    float m2x[4], m2y[4], m2z[4];
#pragma unroll
    for (int c = 0; c < 4; c++) {
        float2 a = sxy[q0 + c];
        float z = sz[q0 + c];
        m2x[c] = -2.f * a.x; m2y[c] = -2.f * a.y; m2z[c] = -2.f * z;
    }

    float v[4][KNN + 1];
#pragma unroll
    for (int c = 0; c < 4; c++) {
#pragma unroll
        for (int s = 0; s < KNN; s++) v[c][s] = INFINITY;
        v[c][KNN] = -INFINITY;
    }

#pragma unroll 2
    for (int g = 0; g < 32; g++) {
        int jb = part + 128 * g;
        float m[4] = {INFINITY, INFINITY, INFINITY, INFINITY};
#pragma unroll
        for (int u = 0; u < 8; u++) {
            int j = jb + 16 * u;
            float2 a = sxy[j];
            float z = sz[j];
            float w = fmaf(z, z, fmaf(a.y, a.y, a.x * a.x));
#pragma unroll
            for (int c = 0; c < 4; c++) {
                float key = fmaf(m2z[c], z, fmaf(m2y[c], a.y, fmaf(m2x[c], a.x, w)));
                m[c] = fminf(m[c], key);
            }
        }
#pragma unroll
        for (int c = 0; c < 4; c++)
#pragma unroll
            for (int s = 0; s < KNN; s++) v[c][s] = med3f(m[c], v[c][s], v[c][s + 1]);
    }

    float tauS[4];
#pragma unroll
    for (int c = 0; c < 4; c++) {
        merge_round(v[c], 1);
        merge_round(v[c], 2);
        merge_round(v[c], 4);
        merge_round(v[c], 8);
        tauS[c] = v[c][0] + TAU_SLACK;
    }

#pragma unroll 2
    for (int mm = 0; mm < 256; mm++) {
        int j = part + 16 * mm;
        float2 a = sxy[j];
        float z = sz[j];
        float w = fmaf(z, z, fmaf(a.y, a.y, a.x * a.x));
#pragma unroll
        for (int c = 0; c < 4; c++) {
            float key = fmaf(m2z[c], z, fmaf(m2y[c], a.y, fmaf(m2x[c], a.x, w)));
            if (key <= tauS[c]) {
                int ql = ql0 + c;
                int pos = atomicAdd(&scnt[ql], 1);
                if (pos < CAP) spairs[ql * CAP + pos] = (unsigned short)j;
            }
        }
    }
    __syncthreads();

    if (tid < 128) {
        int ql = tid;
        int qi = chunk * 128 + ql;
        float2 qa = sxy[qi];
        float qzz = sz[qi];
        float qw = fmaf(qzz, qzz, fmaf(qa.y, qa.y, qa.x * qa.x));
        int cnt = scnt[ql];

        float bd[KNN]; int bi_[KNN];
#pragma unroll
        for (int s = 0; s < KNN; s++) { bd[s] = 3.4e38f; bi_[s] = 0; }
        float worst = 3.4e38f;
        int wslot = 0;
        if (cnt > CAP) {
            for (int j = 0; j < NPTS; j++) {
                float2 a = sxy[j];
                float z = sz[j];
                float w = fmaf(z, z, fmaf(a.y, a.y, a.x * a.x));
                float dot = fmaf(qzz, z, fmaf(qa.y, a.y, qa.x * a.x));
                float d2 = (qw + w) - 2.f * dot;
                if (d2 < worst) {
#pragma unroll
                    for (int s = 0; s < KNN; s++) { if (s == wslot) { bd[s] = d2; bi_[s] = j; } }
                    float wm = bd[0]; int ws = 0;
#pragma unroll
                    for (int s = 1; s < KNN; s++) { if (bd[s] > wm) { wm = bd[s]; ws = s; } }
                    worst = wm; wslot = ws;
                }
            }
        } else {
            for (int t = 0; t < cnt; t++) {
                int j = spairs[ql * CAP + t];
                float2 a = sxy[j];
                float z = sz[j];
                float w = fmaf(z, z, fmaf(a.y, a.y, a.x * a.x));
                float dot = fmaf(qzz, z, fmaf(qa.y, a.y, qa.x * a.x));
                float d2 = (qw + w) - 2.f * dot;
                if (d2 < worst) {
#pragma unroll
                    for (int s = 0; s < KNN; s++) { if (s == wslot) { bd[s] = d2; bi_[s] = j; } }
                    float wm = bd[0]; int ws = 0;
#pragma unroll
                    for (int s = 1; s < KNN; s++) { if (bd[s] > wm) { wm = bd[s]; ws = s; } }
                    worst = wm; wslot = ws;
                }
            }
        }
#pragma unroll
        for (int a = 0; a < KNN - 1; a++)
#pragma unroll
            for (int b2 = 0; b2 < KNN - 1 - a; b2++) {
                bool sw = (bd[b2] > bd[b2 + 1]) ||
                          (bd[b2] == bd[b2 + 1] && bi_[b2] > bi_[b2 + 1]);
                float d_lo = sw ? bd[b2 + 1] : bd[b2];
                float d_hi = sw ? bd[b2] : bd[b2 + 1];
                int   i_lo = sw ? bi_[b2 + 1] : bi_[b2];
                int   i_hi = sw ? bi_[b2] : bi_[b2 + 1];
                bd[b2] = d_lo; bd[b2 + 1] = d_hi; bi_[b2] = i_lo; bi_[b2 + 1] = i_hi;
            }
        float xs[KNN], ys[KNN], zs[KNN];
#pragma unroll
        for (int s = 0; s < KNN; s++) {
            int j = bi_[s];
            float2 a = sxy[j];
            xs[s] = a.x; ys[s] = a.y; zs[s] = sz[j];
        }
        eig_normal3(xs, ys, zs, nv);
    }
    __syncthreads();
}

__global__ __launch_bounds__(512, 4) void normals_kernel(const float* __restrict__ pred,
                                                         const float* __restrict__ gt,
                                                         float* __restrict__ nrm,
                                                         float* __restrict__ out) {
    __shared__ float2 sxy[NPTS];
    __shared__ float  sz[NPTS];
    __shared__ unsigned short spairs_s[128 * CAP];
    __shared__ int scnt_s[128];

    int tid = threadIdx.x;
    int bid = blockIdx.x;
    if (bid == 0 && tid == 0) out[0] = 0.f;
    int cloud = bid >> 8;
    int b = (bid >> 5) & 7;
    int chunk = bid & 31;

    const float* src = (cloud == 0 ? pred : gt) + (size_t)b * 3 * NPTS;
    float nv[3] = {0.f, 0.f, 0.f};
    do_phase_static(src, chunk, tid, sxy, sz, spairs_s, scnt_s, nv);

    if (tid < 128) {
        int qg2 = chunk * 128 + tid;
        float* dst = nrm + ((size_t)cloud * 8 + b) * 3 * NPTS;
        dst[0 * NPTS + qg2] = nv[0];
        dst[1 * NPTS + qg2] = nv[1];
        dst[2 * NPTS + qg2] = nv[2];
    }
}

__global__ __launch_bounds__(256) void loss_kernel(const float* __restrict__ nrm,
                                                   float* __restrict__ out) {
    const int n = NRM_N;
    const float* a = nrm;
    const float* b = nrm + n;
    float acc = 0.f;
    for (int i = blockIdx.x * 256 + threadIdx.x; i < n; i += gridDim.x * 256) {
        float dd = a[i] - b[i];
        acc = fmaf(dd, dd, acc);
    }
#pragma unroll
    for (int off = 32; off > 0; off >>= 1) acc += __shfl_down(acc, off);
    __shared__ float wsum[4];
    int lane = threadIdx.x & 63, wv = threadIdx.x >> 6;
    if (lane == 0) wsum[wv] = acc;
    __syncthreads();
    if (threadIdx.x == 0) {
        float t = wsum[0] + wsum[1] + wsum[2] + wsum[3];
        atomicAdd(out, t * (1.f / (float)n));
    }
}

extern "C" void kernel_launch(void* const* d_in, const int* in_sizes, int n_in,
                              void* d_out, int out_size, void* d_ws, size_t ws_size,
                              hipStream_t stream) {
    (void)in_sizes; (void)n_in; (void)out_size;
    const float* pred = (const float*)d_in[0];
    const float* gt   = (const float*)d_in[1];
    float* out = (float*)d_out;

    size_t need_idx = (size_t)2 * 8 * NPTS * KNN * sizeof(unsigned short); // 1310720
    size_t need_nrm = (size_t)2 * NRM_N * sizeof(float);                   // 786432

    if (ws_size >= need_idx) {
        unsigned short* idx = (unsigned short*)d_ws;
        hipLaunchKernelGGL(knn_idx_kernel, dim3(1024), dim3(512), 0, stream,
                           pred, gt, idx, out);
        hipLaunchKernelGGL(eig_loss_kernel, dim3(512), dim3(128), 0, stream,
                           pred, gt, idx, out);
    } else {
        float* nrm = (float*)d_ws;
        hipLaunchKernelGGL(normals_kernel, dim3(512), dim3(512), 0, stream,
                           pred, gt, nrm, out);
        hipLaunchKernelGGL(loss_kernel, dim3(96), dim3(256), 0, stream, nrm, out);
    }
}

// Round 10
// 165.115 us; speedup vs baseline: 1.0712x; 1.0712x over previous
//
#include <hip/hip_runtime.h>
#include <math.h>

#define NPTS 4096
#define KNN 10
#define CAP 48          // group-8 bound is <=80; overflow -> exact full rescan
#define TAU_SLACK 1e-4f // covers key-vs-d2 rounding skew (~2e-6 abs)
#define NRM_N (8 * 3 * NPTS)
#define QPB 64          // queries per block (1024 blocks)
#define CHUNK 1024      // points staged per LDS round (16 KB)
#define NCH (NPTS / CHUNK)

__device__ __forceinline__ float med3f(float a, float b, float c) {
    return __builtin_amdgcn_fmed3f(a, b, c);
}

// ---------------- LAPACK building blocks (f32, faithful to netlib) ----------
// Fully predicated straight-line leaves (R5, verified absmax 0.0).
// R9 LESSON: hand-packed v_pk_fma_f32 inline asm for the knn keys REGRESSED
// (97 -> 110 us, VALUBusy 85 -> 57%): opaque asm serialized the dependency
// chain and defeated the compiler's interleaving. Scalar fmaf restored.

__device__ __forceinline__ float slapy2_(float x, float y) {
    float ax = fabsf(x), ay = fabsf(y);
    float w = fmaxf(ax, ay), z = fminf(ax, ay);
    float t = z / w;
    float full = w * sqrtf(1.f + t * t);
    return (z == 0.f) ? w : full;
}

__device__ __forceinline__ void slartg_(float f, float g, float* c, float* s, float* r) {
    float f1 = fabsf(f);
    float d = sqrtf(f * f + g * g);
    float rr = copysignf(d, f);
    float ce = f1 / d;
    float se = g / rr;
    bool gz = (g == 0.f), fz = (f == 0.f);
    *c = gz ? 1.f : (fz ? 0.f : ce);
    *s = gz ? 0.f : (fz ? copysignf(1.f, g) : se);
    *r = gz ? f   : (fz ? fabsf(g) : rr);
}

__device__ __forceinline__ void slaev2_(float a, float b, float c,
                                        float* rt1, float* rt2, float* cs1, float* sn1) {
    float sm = a + c;
    float df = a - c;
    float adf = fabsf(df);
    float tb = b + b;
    float ab = fabsf(tb);
    bool agtc = (fabsf(a) > fabsf(c));
    float acmx = agtc ? a : c;
    float acmn = agtc ? c : a;
    float t1 = ab / adf;  float rt_a = adf * sqrtf(1.f + t1 * t1);
    float t2 = adf / ab;  float rt_b = ab * sqrtf(1.f + t2 * t2);
    float rt_c = ab * sqrtf(2.f);
    float rt = (adf > ab) ? rt_a : ((adf < ab) ? rt_b : rt_c);

    float rt1n = 0.5f * (sm - rt);
    float rt1p = 0.5f * (sm + rt);
    float rt2n = (acmx / rt1n) * acmn - (b / rt1n) * b;
    float rt2p = (acmx / rt1p) * acmn - (b / rt1p) * b;
    int sgn1 = (sm < 0.f) ? -1 : 1;
    float r1 = (sm < 0.f) ? rt1n : ((sm > 0.f) ? rt1p : 0.5f * rt);
    float r2 = (sm < 0.f) ? rt2n : ((sm > 0.f) ? rt2p : -0.5f * rt);

    int sgn2 = (df >= 0.f) ? 1 : -1;
    float cs = (df >= 0.f) ? (df + rt) : (df - rt);
    float acs = fabsf(cs);
    float ct = -tb / cs;  float sn1a = 1.f / sqrtf(1.f + ct * ct);  float cs1a = ct * sn1a;
    float tn = -cs / tb;  float cs1b = 1.f / sqrtf(1.f + tn * tn);  float sn1b = tn * cs1b;
    float cs1v = (acs > ab) ? cs1a : ((ab == 0.f) ? 1.f : cs1b);
    float sn1v = (acs > ab) ? sn1a : ((ab == 0.f) ? 0.f : sn1b);
    bool flip = (sgn1 == sgn2);
    *cs1 = flip ? -sn1v : cs1v;
    *sn1 = flip ?  cs1v : sn1v;
    *rt1 = r1;
    *rt2 = r2;
}

// branchless register-select helpers (v_cndmask, never exec-mask branches)
__device__ __forceinline__ float g3v(float a0, float a1, float a2, int i) {
    return i == 0 ? a0 : (i == 1 ? a1 : a2);
}
__device__ __forceinline__ void s3v(float& a0, float& a1, float& a2, int i, float v) {
    a0 = (i == 0) ? v : a0;
    a1 = (i == 1) ? v : a1;
    a2 = (i == 2) ? v : a2;
}
__device__ __forceinline__ float g2v(float a0, float a1, int i) {
    return i == 0 ? a0 : a1;
}
__device__ __forceinline__ void s2v(float& a0, float& a1, int i, float v) {
    a0 = (i == 0) ? v : a0;
    a1 = (i == 1) ? v : a1;
}

// R8: all steqr3 rotations act on ADJACENT columns (jc, jc-1), jc in {1,2}
// -> 2-way selects instead of 3-way. Bit-exact (same expressions).
#define ZROT_ADJ(jc1, C, S)                                                      \
    { float t0_ = (jc1) ? z01 : z02, u0_ = (jc1) ? z00 : z01;                    \
      float nc0_ = (C) * t0_ - (S) * u0_;                                        \
      float nm0_ = (S) * t0_ + (C) * u0_;                                        \
      z00 = (jc1) ? nm0_ : z00; z01 = (jc1) ? nc0_ : nm0_; z02 = (jc1) ? z02 : nc0_; \
      float t1_ = (jc1) ? z11 : z12, u1_ = (jc1) ? z10 : z11;                    \
      float nc1_ = (C) * t1_ - (S) * u1_;                                        \
      float nm1_ = (S) * t1_ + (C) * u1_;                                        \
      z10 = (jc1) ? nm1_ : z10; z11 = (jc1) ? nc1_ : nm1_; z12 = (jc1) ? z12 : nc1_; \
      float t2_ = (jc1) ? z21 : z22, u2_ = (jc1) ? z20 : z21;                    \
      float nc2_ = (C) * t2_ - (S) * u2_;                                        \
      float nm2_ = (S) * t2_ + (C) * u2_;                                        \
      z20 = (jc1) ? nm2_ : z20; z21 = (jc1) ? nc2_ : nm2_; z22 = (jc1) ? z22 : nc2_; }

#define ZSWAP(ja, jb)                                                            \
    { float t0_ = g3v(z00, z01, z02, (ja));                                      \
      s3v(z00, z01, z02, (ja), g3v(z00, z01, z02, (jb)));                        \
      s3v(z00, z01, z02, (jb), t0_);                                             \
      float t1_ = g3v(z10, z11, z12, (ja));                                      \
      s3v(z10, z11, z12, (ja), g3v(z10, z11, z12, (jb)));                        \
      s3v(z10, z11, z12, (jb), t1_);                                             \
      float t2_ = g3v(z20, z21, z22, (ja));                                      \
      s3v(z20, z21, z22, (ja), g3v(z20, z21, z22, (jb)));                        \
      s3v(z20, z21, z22, (jb), t2_); }

__device__ void steqr3_reg(float& d0, float& d1, float& d2,
                           float& e0, float& e1,
                           float& z00, float& z01, float& z02,
                           float& z10, float& z11, float& z12,
                           float& z20, float& z21, float& z22) {
    const float eps    = 5.9604644775390625e-8f;  // 2^-24
    const float eps2   = eps * eps;
    const float safmin = 1.17549435e-38f;
    const int n = 3, nm1 = 2;
    const int nmaxit = 90;
    int jtot = 0, l1 = 1;
    int guard = 0;

#define DGET(i)    g3v(d0, d1, d2, (i))
#define DSET(i, v) s3v(d0, d1, d2, (i), (v))
#define EGET(i)    g2v(e0, e1, (i))
#define ESET(i, v) s2v(e0, e1, (i), (v))

    while (l1 <= n) {
        if (++guard > 600) break;
        if (l1 > 1) ESET(l1 - 2, 0.f);
        int m = n;
        if (l1 <= nm1) {
            for (int mm = l1; mm <= nm1; ++mm) {
                float tst = fabsf(EGET(mm - 1));
                if (tst == 0.f) { m = mm; break; }
                if (tst <= (sqrtf(fabsf(DGET(mm - 1))) * sqrtf(fabsf(DGET(mm)))) * eps) {
                    ESET(mm - 1, 0.f); m = mm; break;
                }
            }
        }
        int l = l1, lsv = l1, lend = m, lendsv = m;
        l1 = m + 1;
        if (lend == l) continue;
        float anorm = 0.f;
        for (int i = l; i <= lend; i++) anorm = fmaxf(anorm, fabsf(DGET(i - 1)));
        for (int i = l; i <= lend - 1; i++) anorm = fmaxf(anorm, fabsf(EGET(i - 1)));
        if (anorm == 0.f) continue;
        if (fabsf(DGET(lend - 1)) < fabsf(DGET(l - 1))) { lend = lsv; l = lendsv; }

        if (lend > l) {
            for (;;) {
                if (++guard > 600) return;
                int m2 = lend;
                if (l != lend) {
                    for (int mm = l; mm <= lend - 1; ++mm) {
                        float tst = EGET(mm - 1) * EGET(mm - 1);
                        if (tst <= (eps2 * fabsf(DGET(mm - 1))) * fabsf(DGET(mm)) + safmin) { m2 = mm; break; }
                    }
                }
                if (m2 < lend) ESET(m2 - 1, 0.f);
                float p = DGET(l - 1);
                if (m2 == l) {
                    DSET(l - 1, p); l = l + 1;
                    if (l <= lend) continue;
                    break;
                }
                if (m2 == l + 1) {
                    float rt1, rt2, c, s;
                    slaev2_(DGET(l - 1), EGET(l - 1), DGET(l), &rt1, &rt2, &c, &s);
                    ZROT_ADJ(l == 1, c, s);                 // cols (l, l-1)
                    DSET(l - 1, rt1); DSET(l, rt2); ESET(l - 1, 0.f);
                    l += 2;
                    if (l <= lend) continue;
                    break;
                }
                if (jtot == nmaxit) break;
                jtot++;
                float g = (DGET(l) - p) / (2.f * EGET(l - 1));
                float r = slapy2_(g, 1.f);
                g = DGET(m2 - 1) - p + EGET(l - 1) / (g + copysignf(r, g));
                float s = 1.f, c = 1.f;
                p = 0.f;
                float cs0 = 0.f, cs1 = 0.f, sn0 = 0.f, sn1 = 0.f;
                for (int i = m2 - 1; i >= l; --i) {
                    float f = s * EGET(i - 1);
                    float b = c * EGET(i - 1);
                    slartg_(g, f, &c, &s, &r);
                    if (i != m2 - 1) ESET(i, r);
                    g = DGET(i) - p;
                    r = (DGET(i - 1) - g) * s + 2.f * c * b;
                    p = s * r;
                    DSET(i, g + p);
                    g = c * r - b;
                    s2v(cs0, cs1, i - l, c); s2v(sn0, sn1, i - l, -s);
                }
                int nrot = m2 - l;
                for (int j = nrot; j >= 1; --j) {
                    float C = g2v(cs0, cs1, j - 1), S = g2v(sn0, sn1, j - 1);
                    ZROT_ADJ(l - 1 + j == 1, C, S);         // cols (l-1+j, l-2+j)
                }
                DSET(l - 1, DGET(l - 1) - p);
                ESET(l - 1, g);
            }
        } else {
            for (;;) {
                if (++guard > 600) return;
                int m2 = lend;
                if (l != lend) {
                    for (int mm = l; mm >= lend + 1; --mm) {
                        float tst = EGET(mm - 2) * EGET(mm - 2);
                        if (tst <= (eps2 * fabsf(DGET(mm - 1))) * fabsf(DGET(mm - 2)) + safmin) { m2 = mm; break; }
                    }
                }
                if (m2 > lend) ESET(m2 - 2, 0.f);
                float p = DGET(l - 1);
                if (m2 == l) {
                    DSET(l - 1, p); l = l - 1;
                    if (l >= lend) continue;
                    break;
                }
                if (m2 == l - 1) {
                    float rt1, rt2, c, s;
                    slaev2_(DGET(l - 2), EGET(l - 2), DGET(l - 1), &rt1, &rt2, &c, &s);
                    ZROT_ADJ(l == 2, c, s);                 // cols (l-1, l-2)
                    DSET(l - 2, rt1); DSET(l - 1, rt2); ESET(l - 2, 0.f);
                    l -= 2;
                    if (l >= lend) continue;
                    break;
                }
                if (jtot == nmaxit) break;
                jtot++;
                float g = (DGET(l - 2) - p) / (2.f * EGET(l - 2));
                float r = slapy2_(g, 1.f);
                g = DGET(m2 - 1) - p + EGET(l - 2) / (g + copysignf(r, g));
                float s = 1.f, c = 1.f;
                p = 0.f;
                float cs0 = 0.f, cs1 = 0.f, sn0 = 0.f, sn1 = 0.f;
                for (int i = m2; i <= l - 1; ++i) {
                    float f = s * EGET(i - 1);
                    float b = c * EGET(i - 1);
                    slartg_(g, f, &c, &s, &r);
                    if (i != m2) ESET(i - 2, r);
                    g = DGET(i - 1) - p;
                    r = (DGET(i) - g) * s + 2.f * c * b;
                    p = s * r;
                    DSET(i - 1, g + p);
                    g = c * r - b;
                    s2v(cs0, cs1, i - m2, c); s2v(sn0, sn1, i - m2, s);
                }
                int nrot = l - m2;
                for (int j = 1; j <= nrot; ++j) {
                    float C = g2v(cs0, cs1, j - 1), S = g2v(sn0, sn1, j - 1);
                    ZROT_ADJ(m2 - 1 + j == 1, C, S);        // cols (m2-1+j, m2-2+j)
                }
                DSET(l - 1, DGET(l - 1) - p);
                ESET(l - 2, g);
            }
        }
    }
    for (int ii = 2; ii <= n; ++ii) {
        int i = ii - 1, k = i;
        float p = DGET(i - 1);
        for (int j = ii; j <= n; ++j) {
            bool lt = (DGET(j - 1) < p);
            k = lt ? j : k;
            p = lt ? DGET(j - 1) : p;
        }
        DSET(k - 1, DGET(i - 1)); DSET(i - 1, p);
        ZSWAP(i - 1, k - 1);
    }
#undef DGET
#undef DSET
#undef EGET
#undef ESET
}

__device__ void eig_normal3(const float xs[KNN], const float ys[KNN], const float zs[KNN],
                            float out[3]) {
    float mx = 0.f, my = 0.f, mz = 0.f;
#pragma unroll
    for (int s = 0; s < KNN; s++) { mx += xs[s]; my += ys[s]; mz += zs[s]; }
    mx /= 10.0f; my /= 10.0f; mz /= 10.0f;

    float c00 = 0.f, c10 = 0.f, c20 = 0.f, c11 = 0.f, c21 = 0.f, c22 = 0.f;
#pragma unroll
    for (int s = 0; s < KNN; s++) {
        float dx = xs[s] - mx, dy = ys[s] - my, dz = zs[s] - mz;
        c00 = fmaf(dx, dx, c00);
        c10 = fmaf(dy, dx, c10);
        c20 = fmaf(dz, dx, c20);
        c11 = fmaf(dy, dy, c11);
        c21 = fmaf(dz, dy, c21);
        c22 = fmaf(dz, dz, c22);
    }
    c00 /= 10.0f; c10 /= 10.0f; c20 /= 10.0f; c11 /= 10.0f; c21 /= 10.0f; c22 /= 10.0f;

    float alpha = c10, x2 = c20;
    float xnorm = fabsf(x2);
    bool xz = (xnorm == 0.f);
    float beta_f = -copysignf(slapy2_(alpha, xnorm), alpha);
    float tau_f  = (beta_f - alpha) / beta_f;
    float v2_f   = x2 / (alpha - beta_f);
    float tau  = xz ? 0.f : tau_f;
    float v2   = xz ? 0.f : v2_f;
    float beta = xz ? alpha : beta_f;

    bool tz = (tau != 0.f);
    float p0 = tau * (c11 + c21 * v2);
    float p1 = tau * (c21 + c22 * v2);
    float aw = -0.5f * tau * (p0 + p1 * v2);
    float w0 = p0 + aw;
    float w1 = p1 + aw * v2;
    float d0c = c00;
    float d1c = tz ? ((c11 - w0) - w0)            : c11;
    float e1c = tz ? ((c21 - v2 * w0) - w1)       : c21;
    float d2c = tz ? ((c22 - v2 * w1) - w1 * v2)  : c22;
    float e0c = beta;

    float z00 = 1.f, z01 = 0.f, z02 = 0.f;
    float z10 = 0.f, z11 = 1.f, z12 = 0.f;
    float z20 = 0.f, z21 = 0.f, z22 = 1.f;
    steqr3_reg(d0c, d1c, d2c, e0c, e1c,
               z00, z01, z02, z10, z11, z12, z20, z21, z22);

    float y0 = z00, y1 = z10, y2 = z20;
    float t = tau * (y1 + v2 * y2);
    float y1b = y1 - t;
    float y2b = y2 - t * v2;
    out[0] = y0;
    out[1] = tz ? y1b : y1;
    out[2] = tz ? y2b : y2;
}

__device__ __forceinline__ void merge_round(float* v, int off) {
    float t[KNN];
#pragma unroll
    for (int i = 0; i < KNN; i++) t[i] = fminf(v[i], __shfl_xor(v[KNN - 1 - i], off));
#define CE(a, b) { float hi = fmaxf(t[a], t[b]); float lo = fminf(t[a], t[b]); t[a] = hi; t[b] = lo; }
    CE(0, 8) CE(1, 9)
    CE(0, 4) CE(1, 5) CE(2, 6) CE(3, 7)
    CE(0, 2) CE(1, 3) CE(4, 6) CE(5, 7)
    CE(0, 1) CE(2, 3) CE(4, 5) CE(6, 7) CE(8, 9)
#undef CE
#pragma unroll
    for (int i = 0; i < KNN; i++) v[i] = t[i];
}

// ---------------- kernel 1: kNN selection -> sorted top-10 indices ----------
// R5-verbatim (verified absmax 0.0, ~97us): 1024 blocks x 512 threads, 64
// queries/block, c=2, chunked 16 KB staging, scalar fmaf keys (R9 lesson).
__global__ __launch_bounds__(512, 8) void knn_idx_kernel(const float* __restrict__ pred,
                                                         const float* __restrict__ gt,
                                                         unsigned short* __restrict__ idxout,
                                                         float* __restrict__ out) {
    __shared__ float4 pts[CHUNK];                 // 16384 B
    __shared__ unsigned short spairs[QPB * CAP];  // 6144 B
    __shared__ int scnt[QPB];                     // 256 B

    int tid = threadIdx.x;
    int bid = blockIdx.x;
    if (bid == 0 && tid == 0) out[0] = 0.f;   // zero for eig_loss's atomicAdd
    int cloud = bid >> 9;       // 0..1
    int b = (bid >> 6) & 7;     // 0..7
    int chunkq = bid & 63;      // 0..63  query chunk

    const float* src = (cloud == 0 ? pred : gt) + (size_t)b * 3 * NPTS;

    int part = tid & 15;        // 0..15
    int qg = tid >> 4;          // 0..31
    int ql0 = qg * 2;
    int q0 = chunkq * QPB + ql0;

    if (tid < QPB) scnt[tid] = 0;   // consumed only after pass-2 barriers

    // query coords straight from global (identical bits to staged values)
    float m2x[2], m2y[2], m2z[2];
#pragma unroll
    for (int c = 0; c < 2; c++) {
        float x = src[q0 + c], y = src[NPTS + q0 + c], z = src[2 * NPTS + q0 + c];
        m2x[c] = -2.f * x; m2y[c] = -2.f * y; m2z[c] = -2.f * z;
    }

    // ---- pass 1: med3 chain over 8-candidate group-min keys (chunked) ------
    float v[2][KNN + 1];
#pragma unroll
    for (int c = 0; c < 2; c++) {
#pragma unroll
        for (int s = 0; s < KNN; s++) v[c][s] = INFINITY;
        v[c][KNN] = -INFINITY;
    }

    for (int h = 0; h < NCH; h++) {
        if (h) __syncthreads();           // previous chunk fully consumed
        for (int j2 = tid; j2 < CHUNK; j2 += 512) {
            int j = h * CHUNK + j2;
            float x = src[j], y = src[NPTS + j], z = src[2 * NPTS + j];
            float w = fmaf(z, z, fmaf(y, y, x * x));
            pts[j2] = make_float4(x, y, z, w);
        }
        __syncthreads();
#pragma unroll 2
        for (int g2 = 0; g2 < 8; g2++) {  // global group = h*8+g2, ascending
            int jb = part + 128 * g2;
            float m[2] = {INFINITY, INFINITY};
#pragma unroll
            for (int u = 0; u < 8; u++) {
                float4 p = pts[jb + 16 * u];
#pragma unroll
                for (int c = 0; c < 2; c++) {
                    float key = fmaf(m2z[c], p.z, fmaf(m2y[c], p.y, fmaf(m2x[c], p.x, p.w)));
                    m[c] = fminf(m[c], key);
                }
            }
#pragma unroll
            for (int c = 0; c < 2; c++)
#pragma unroll
                for (int s = 0; s < KNN; s++) v[c][s] = med3f(m[c], v[c][s], v[c][s + 1]);
        }
    }

    // ---- merge the 16 part-lists (4 xor rounds) -> tau ---------------------
    float tauS[2];
#pragma unroll
    for (int c = 0; c < 2; c++) {
        merge_round(v[c], 1);
        merge_round(v[c], 2);
        merge_round(v[c], 4);
        merge_round(v[c], 8);
        tauS[c] = v[c][0] + TAU_SLACK;
    }

    // ---- pass 2: collect idx with key <= tau+slack (restaged chunks) -------
    for (int h = 0; h < NCH; h++) {
        __syncthreads();                  // pass-1 (or prev collect) done
        for (int j2 = tid; j2 < CHUNK; j2 += 512) {
            int j = h * CHUNK + j2;
            float x = src[j], y = src[NPTS + j], z = src[2 * NPTS + j];
            float w = fmaf(z, z, fmaf(y, y, x * x));
            pts[j2] = make_float4(x, y, z, w);
        }
        __syncthreads();
#pragma unroll 2
        for (int mm = 0; mm < 64; mm++) { // j ascending per part, as before
            int j2 = part + 16 * mm;
            float4 p = pts[j2];
#pragma unroll
            for (int c = 0; c < 2; c++) {
                float key = fmaf(m2z[c], p.z, fmaf(m2y[c], p.y, fmaf(m2x[c], p.x, p.w)));
                if (key <= tauS[c]) {
                    int ql = ql0 + c;
                    int pos = atomicAdd(&scnt[ql], 1);
                    if (pos < CAP) spairs[ql * CAP + pos] = (unsigned short)(h * CHUNK + j2);
                }
            }
        }
    }
    __syncthreads();

    // ---- tail: exact top-10 by reference (d2, idx), wave 0, global reads ---
    if (tid < QPB) {
        int ql = tid;
        int qi = chunkq * QPB + ql;
        float qx = src[qi], qy = src[NPTS + qi], qz = src[2 * NPTS + qi];
        float qw = fmaf(qz, qz, fmaf(qy, qy, qx * qx));
        int cnt = scnt[ql];

        float bd[KNN]; int bi_[KNN];
#pragma unroll
        for (int s = 0; s < KNN; s++) { bd[s] = 3.4e38f; bi_[s] = 0; }
        float worst = 3.4e38f;
        int wslot = 0;
        if (cnt > CAP) {
            // overflow: exact full rescan from global (correctness net)
            for (int j = 0; j < NPTS; j++) {
                float x = src[j], y = src[NPTS + j], z = src[2 * NPTS + j];
                float w = fmaf(z, z, fmaf(y, y, x * x));
                float dot = fmaf(qz, z, fmaf(qy, y, qx * x));
                float d2 = (qw + w) - 2.f * dot;
                if (d2 < worst) {
#pragma unroll
                    for (int s = 0; s < KNN; s++) { if (s == wslot) { bd[s] = d2; bi_[s] = j; } }
                    float wm = bd[0]; int ws = 0;
#pragma unroll
                    for (int s = 1; s < KNN; s++) { if (bd[s] > wm) { wm = bd[s]; ws = s; } }
                    worst = wm; wslot = ws;
                }
            }
        } else {
            for (int t = 0; t < cnt; t++) {
                int j = spairs[ql * CAP + t];
                float x = src[j], y = src[NPTS + j], z = src[2 * NPTS + j];
                float w = fmaf(z, z, fmaf(y, y, x * x));
                float dot = fmaf(qz, z, fmaf(qy, y, qx * x));
                float d2 = (qw + w) - 2.f * dot;
                if (d2 < worst) {
#pragma unroll
                    for (int s = 0; s < KNN; s++) { if (s == wslot) { bd[s] = d2; bi_[s] = j; } }
                    float wm = bd[0]; int ws = 0;
#pragma unroll
                    for (int s = 1; s < KNN; s++) { if (bd[s] > wm) { wm = bd[s]; ws = s; } }
                    worst = wm; wslot = ws;
                }
            }
        }
        // sort by (d2, idx) ascending == jax.lax.top_k order
#pragma unroll
        for (int a = 0; a < KNN - 1; a++)
#pragma unroll
            for (int b2 = 0; b2 < KNN - 1 - a; b2++) {
                bool sw = (bd[b2] > bd[b2 + 1]) ||
                          (bd[b2] == bd[b2 + 1] && bi_[b2] > bi_[b2 + 1]);
                float d_lo = sw ? bd[b2 + 1] : bd[b2];
                float d_hi = sw ? bd[b2] : bd[b2 + 1];
                int   i_lo = sw ? bi_[b2 + 1] : bi_[b2];
                int   i_hi = sw ? bi_[b2] : bi_[b2 + 1];
                bd[b2] = d_lo; bd[b2 + 1] = d_hi; bi_[b2] = i_lo; bi_[b2 + 1] = i_hi;
            }
        size_t qglobal = ((size_t)cloud * 8 + b) * NPTS + qi;
#pragma unroll
        for (int s = 0; s < KNN; s++)
            idxout[qglobal * KNN + s] = (unsigned short)bi_[s];
    }
}

// ---------------- kernel 2: fused gather + cov + eig + loss -----------------
// R5-verified structure (512 blocks x 128 threads, wave0=pred/wave1=gt pairing
// through LDS, one atomicAdd per block). Latency/issue optimum at 1 wave/SIMD
// (R5/R6 model: I~18us, L~18us, k_opt=1). Body: R8 ZROT_ADJ.
#define PAIRS_PB 64
__global__ __launch_bounds__(128) void eig_loss_kernel(const float* __restrict__ pred,
                                                       const float* __restrict__ gt,
                                                       const unsigned short* __restrict__ idxin,
                                                       float* __restrict__ out) {
    __shared__ float nl[128][3];

    int t = threadIdx.x;
    int cloud = t >> 6;                        // wave 0: pred, wave 1: gt
    int pr = blockIdx.x * PAIRS_PB + (t & 63); // pair id 0..32767
    int b = pr >> 12;
    int pt = pr & 4095;
    const float* src = (cloud == 0 ? pred : gt) + (size_t)b * 3 * NPTS;
    size_t qglobal = ((size_t)cloud * 8 + b) * NPTS + pt;

    float xs[KNN], ys[KNN], zs[KNN];
#pragma unroll
    for (int s = 0; s < KNN; s++) {
        int j = idxin[qglobal * KNN + s];
        xs[s] = src[j]; ys[s] = src[NPTS + j]; zs[s] = src[2 * NPTS + j];
    }
    float nv[3];
    eig_normal3(xs, ys, zs, nv);
    nl[t][0] = nv[0]; nl[t][1] = nv[1]; nl[t][2] = nv[2];
    __syncthreads();

    if (t < 64) {
        float acc = 0.f;
#pragma unroll
        for (int k = 0; k < 3; k++) {
            float dd = nl[t][k] - nl[t + 64][k];
            acc = fmaf(dd, dd, acc);
        }
#pragma unroll
        for (int off = 32; off > 0; off >>= 1) acc += __shfl_down(acc, off);
        if (t == 0) atomicAdd(out, acc * (1.f / (float)NRM_N));
    }
}

// ---------------- R11-verbatim static fallback (ws-too-small path) ----------
__device__ void do_phase_static(const float* __restrict__ src, int chunk, int tid,
                                float2* sxy, float* sz, unsigned short* spairs, int* scnt,
                                float nv[3]) {
    for (int j = tid; j < NPTS; j += 512) {
        float x = src[j], y = src[NPTS + j], z = src[2 * NPTS + j];
        sxy[j] = make_float2(x, y);
        sz[j] = z;
    }
    if (tid < 128) scnt[tid] = 0;
    __syncthreads();

    int part = tid & 15;
    int qg = tid >> 4;
    int ql0 = qg * 4;
    int q0 = chunk * 128 + ql0;

    float m2x[4], m2y[4], m2z[4];
#pragma unroll
    for (int c = 0; c < 4; c++) {
        float2 a = sxy[q0 + c];
        float z = sz[q0 + c];
        m2x[c] = -2.f * a.x; m2y[c] = -2.f * a.y; m2z[c] = -2.f * z;
    }

    float v[4][KNN + 1];
#pragma unroll
    for (int c = 0; c < 4; c++) {
#pragma unroll
        for (int s = 0; s < KNN; s++) v[c][s] = INFINITY;
        v[c][KNN] = -INFINITY;
    }

#pragma unroll 2
    for (int g = 0; g < 32; g++) {
        int jb = part + 128 * g;
        float m[4] = {INFINITY, INFINITY, INFINITY, INFINITY};
#pragma unroll
        for (int u = 0; u < 8; u++) {
            int j = jb + 16 * u;
            float2 a = sxy[j];
            float z = sz[j];
            float w = fmaf(z, z, fmaf(a.y, a.y, a.x * a.x));
#pragma unroll
            for (int c = 0; c < 4; c++) {
                float key = fmaf(m2z[c], z, fmaf(m2y[c], a.y, fmaf(m2x[c], a.x, w)));
                m[c] = fminf(m[c], key);
            }
        }
#pragma unroll
        for (int c = 0; c < 4; c++)
#pragma unroll
            for (int s = 0; s < KNN; s++) v[c][s] = med3f(m[c], v[c][s], v[c][s + 1]);
    }

    float tauS[4];
#pragma unroll
    for (int c = 0; c < 4; c++) {
        merge_round(v[c], 1);
        merge_round(v[c], 2);
        merge_round(v[c], 4);
        merge_round(v[c], 8);
        tauS[c] = v[c][0] + TAU_SLACK;
    }

#pragma unroll 2
    for (int mm = 0; mm < 256; mm++) {
        int j = part + 16 * mm;
        float2 a = sxy[j];
        float z = sz[j];
        float w = fmaf(z, z, fmaf(a.y, a.y, a.x * a.x));
#pragma unroll
        for (int c = 0; c < 4; c++) {
            float key = fmaf(m2z[c], z, fmaf(m2y[c], a.y, fmaf(m2x[c], a.x, w)));
            if (key <= tauS[c]) {
                int ql = ql0 + c;
                int pos = atomicAdd(&scnt[ql], 1);
                if (pos < CAP) spairs[ql * CAP + pos] = (unsigned short)j;
            }
        }
    }
    __syncthreads();

    if (tid < 128) {
        int ql = tid;
        int qi = chunk * 128 + ql;
        float2 qa = sxy[qi];
        float qzz = sz[qi];
        float qw = fmaf(qzz, qzz, fmaf(qa.y, qa.y, qa.x * qa.x));
        int cnt = scnt[ql];

        float bd[KNN]; int bi_[KNN];
#pragma unroll
        for (int s = 0; s < KNN; s++) { bd[s] = 3.4e38f; bi_[s] = 0; }
        float worst = 3.4e38f;
        int wslot = 0;
        if (cnt > CAP) {
            for (int j = 0; j < NPTS; j++) {
                float2 a = sxy[j];
                float z = sz[j];
                float w = fmaf(z, z, fmaf(a.y, a.y, a.x * a.x));
                float dot = fmaf(qzz, z, fmaf(qa.y, a.y, qa.x * a.x));
                float d2 = (qw + w) - 2.f * dot;
                if (d2 < worst) {
#pragma unroll
                    for (int s = 0; s < KNN; s++) { if (s == wslot) { bd[s] = d2; bi_[s] = j; } }
                    float wm = bd[0]; int ws = 0;
#pragma unroll
                    for (int s = 1; s < KNN; s++) { if (bd[s] > wm) { wm = bd[s]; ws = s; } }
                    worst = wm; wslot = ws;
                }
            }
        } else {
            for (int t = 0; t < cnt; t++) {
                int j = spairs[ql * CAP + t];
                float2 a = sxy[j];
                float z = sz[j];
                float w = fmaf(z, z, fmaf(a.y, a.y, a.x * a.x));
                float dot = fmaf(qzz, z, fmaf(qa.y, a.y, qa.x * a.x));
                float d2 = (qw + w) - 2.f * dot;
                if (d2 < worst) {
#pragma unroll
                    for (int s = 0; s < KNN; s++) { if (s == wslot) { bd[s] = d2; bi_[s] = j; } }
                    float wm = bd[0]; int ws = 0;
#pragma unroll
                    for (int s = 1; s < KNN; s++) { if (bd[s] > wm) { wm = bd[s]; ws = s; } }
                    worst = wm; wslot = ws;
                }
            }
        }
#pragma unroll
        for (int a = 0; a < KNN - 1; a++)
#pragma unroll
            for (int b2 = 0; b2 < KNN - 1 - a; b2++) {
                bool sw = (bd[b2] > bd[b2 + 1]) ||
                          (bd[b2] == bd[b2 + 1] && bi_[b2] > bi_[b2 + 1]);
                float d_lo = sw ? bd[b2 + 1] : bd[b2];
                float d_hi = sw ? bd[b2] : bd[b2 + 1];
                int   i_lo = sw ? bi_[b2 + 1] : bi_[b2];
                int   i_hi = sw ? bi_[b2] : bi_[b2 + 1];
                bd[b2] = d_lo; bd[b2 + 1] = d_hi; bi_[b2] = i_lo; bi_[b2 + 1] = i_hi;
            }
        float xs[KNN], ys[KNN], zs[KNN];
#pragma unroll
        for (int s = 0; s < KNN; s++) {
            int j = bi_[s];
            float2 a = sxy[j];
            xs[s] = a.x; ys[s] = a.y; zs[s] = sz[j];
        }
        eig_normal3(xs, ys, zs, nv);
    }
    __syncthreads();
}

__global__ __launch_bounds__(512, 4) void normals_kernel(const float* __restrict__ pred,
                                                         const float* __restrict__ gt,
                                                         float* __restrict__ nrm,
                                                         float* __restrict__ out) {
    __shared__ float2 sxy[NPTS];
    __shared__ float  sz[NPTS];
    __shared__ unsigned short spairs_s[128 * CAP];
    __shared__ int scnt_s[128];

    int tid = threadIdx.x;
    int bid = blockIdx.x;
    if (bid == 0 && tid == 0) out[0] = 0.f;
    int cloud = bid >> 8;
    int b = (bid >> 5) & 7;
    int chunk = bid & 31;

    const float* src = (cloud == 0 ? pred : gt) + (size_t)b * 3 * NPTS;
    float nv[3] = {0.f, 0.f, 0.f};
    do_phase_static(src, chunk, tid, sxy, sz, spairs_s, scnt_s, nv);

    if (tid < 128) {
        int qg2 = chunk * 128 + tid;
        float* dst = nrm + ((size_t)cloud * 8 + b) * 3 * NPTS;
        dst[0 * NPTS + qg2] = nv[0];
        dst[1 * NPTS + qg2] = nv[1];
        dst[2 * NPTS + qg2] = nv[2];
    }
}

__global__ __launch_bounds__(256) void loss_kernel(const float* __restrict__ nrm,
                                                   float* __restrict__ out) {
    const int n = NRM_N;
    const float* a = nrm;
    const float* b = nrm + n;
    float acc = 0.f;
    for (int i = blockIdx.x * 256 + threadIdx.x; i < n; i += gridDim.x * 256) {
        float dd = a[i] - b[i];
        acc = fmaf(dd, dd, acc);
    }
#pragma unroll
    for (int off = 32; off > 0; off >>= 1) acc += __shfl_down(acc, off);
    __shared__ float wsum[4];
    int lane = threadIdx.x & 63, wv = threadIdx.x >> 6;
    if (lane == 0) wsum[wv] = acc;
    __syncthreads();
    if (threadIdx.x == 0) {
        float t = wsum[0] + wsum[1] + wsum[2] + wsum[3];
        atomicAdd(out, t * (1.f / (float)n));
    }
}

extern "C" void kernel_launch(void* const* d_in, const int* in_sizes, int n_in,
                              void* d_out, int out_size, void* d_ws, size_t ws_size,
                              hipStream_t stream) {
    (void)in_sizes; (void)n_in; (void)out_size;
    const float* pred = (const float*)d_in[0];
    const float* gt   = (const float*)d_in[1];
    float* out = (float*)d_out;

    size_t need_idx = (size_t)2 * 8 * NPTS * KNN * sizeof(unsigned short); // 1310720
    size_t need_nrm = (size_t)2 * NRM_N * sizeof(float);                   // 786432

    if (ws_size >= need_idx) {
        unsigned short* idx = (unsigned short*)d_ws;
        hipLaunchKernelGGL(knn_idx_kernel, dim3(1024), dim3(512), 0, stream,
                           pred, gt, idx, out);
        hipLaunchKernelGGL(eig_loss_kernel, dim3(512), dim3(128), 0, stream,
                           pred, gt, idx, out);
    } else {
        float* nrm = (float*)d_ws;
        hipLaunchKernelGGL(normals_kernel, dim3(512), dim3(512), 0, stream,
                           pred, gt, nrm, out);
        hipLaunchKernelGGL(loss_kernel, dim3(96), dim3(256), 0, stream, nrm, out);
    }
}